// Round 5
// baseline (333.555 us; speedup 1.0000x reference)
//
#include <hip/hip_runtime.h>
#include <hip/hip_bf16.h>
#include <math.h>

#define DIM 2048
#define NH 32
#define NKV 8
#define HD 64
#define SEQ 2048
#define BATCH 2
#define MTOT (BATCH*SEQ)          // 4096
#define QKV_N ((NH + 2*NKV)*HD)   // 3072
#define QSCALE 0.18033688011112042f   // log2(e)/8

typedef __bf16 bf16x8 __attribute__((ext_vector_type(8)));
typedef float f32x4 __attribute__((ext_vector_type(4)));

#if __has_builtin(__builtin_amdgcn_exp2f)
#define EXP2F __builtin_amdgcn_exp2f
#else
#define EXP2F exp2f
#endif

__device__ __forceinline__ void gld_lds16(const void* g, void* l) {
  __builtin_amdgcn_global_load_lds((__attribute__((address_space(1))) void*)g,
                                   (__attribute__((address_space(3))) void*)l,
                                   16, 0, 0);
}

// Phase sync primitives (8-phase template). Fused asm so nothing is scheduled
// between the waitcnt and the barrier.
#define MIDBAR     asm volatile("s_barrier" ::: "memory")
#define ENDBAR     asm volatile("s_barrier" ::: "memory")
#define ENDBAR_VM0 asm volatile("s_waitcnt vmcnt(0)\n\ts_barrier" ::: "memory")
// 2-phase (wo kernel) counted sync, carried from R4:
#define PHASE_SYNC4 asm volatile("s_waitcnt vmcnt(4)\n\ts_barrier" ::: "memory")
#define PHASE_SYNC0 asm volatile("s_waitcnt vmcnt(0)\n\ts_barrier" ::: "memory")
#define POST_SYNC   asm volatile("s_waitcnt lgkmcnt(0)\n\ts_barrier" ::: "memory")

// ---------------- elementwise: fp32 -> bf16 ----------------
__global__ void cvt_x_kernel(const float* __restrict__ src, __hip_bfloat16* __restrict__ dst, int n4) {
  int i = blockIdx.x * 256 + threadIdx.x;
  if (i >= n4) return;
  float4 v = ((const float4*)src)[i];
  union { __hip_bfloat16 h[4]; uint2 u; } t;
  t.h[0] = __float2bfloat16(v.x); t.h[1] = __float2bfloat16(v.y);
  t.h[2] = __float2bfloat16(v.z); t.h[3] = __float2bfloat16(v.w);
  ((uint2*)dst)[i] = t.u;
}

// ---------------- transpose + convert: src R x C fp32 -> dst C x R bf16 ----------------
__global__ void transpose_cvt_kernel(const float* __restrict__ src, __hip_bfloat16* __restrict__ dst,
                                     int R, int C) {
  __shared__ float tile[32][33];
  int c0 = blockIdx.x * 32, r0 = blockIdx.y * 32;
  int tx = threadIdx.x & 31, ty = threadIdx.x >> 5;
  #pragma unroll
  for (int i = ty; i < 32; i += 8)
    tile[i][tx] = src[(size_t)(r0 + i) * C + c0 + tx];
  __syncthreads();
  #pragma unroll
  for (int i = ty; i < 32; i += 8)
    dst[(size_t)(c0 + i) * R + r0 + tx] = __float2bfloat16(tile[tx][i]);
}

// ---------------- QKV GEMM: 256x256 tile, 8 waves, BK=64, 8-phase schedule, fused RoPE ----------
// LDS 128 KB: per matrix (A then B at elt 32768): 2 dbuf x 2 half x 2 subpanel([128][32]) x 8 KB.
// st_16x32 swizzle: phys_byte = logical_byte ^ ((logical_byte>>9)&1)<<5 (involution; applied
// on the pre-swizzled global SOURCE of global_load_lds and on the ds_read address).
// Per K-tile (64) = 4 quadrant phases: (mh,nh) = (0,0),(0,1),(1,1),(1,0); 16 MFMA each.
// Stage tile T+1 into freed buffer during T's phases (A-h0@q0, A-h1@q1, B-h0@q2, B-h1@q2);
// single vmcnt(0) drain fused into q3's end barrier (last stage issued >=1 phase earlier).
// Region safety: A subpanels of T-1 last read at q2, B at q3; all stage targets freed by
// a preceding end-barrier. grid 192 (16x12), XCD-swizzled bijective.
__global__ __launch_bounds__(512, 2) void gemm_qkv_rope_kernel(const __hip_bfloat16* __restrict__ A,
                                                               const __hip_bfloat16* __restrict__ Bt,
                                                               const float* __restrict__ freqs,
                                                               __hip_bfloat16* __restrict__ Qb,
                                                               __hip_bfloat16* __restrict__ Kb,
                                                               __hip_bfloat16* __restrict__ Vb) {
  __shared__ __hip_bfloat16 lds[65536];   // 128 KB
  const int tid = threadIdx.x;
  const int w = tid >> 6, lane = tid & 63, ln = lane & 15, quad = lane >> 4;
  const int wr = w >> 2, wc = w & 3;      // 2M x 4N wave grid; per-wave out 128x64
  const int id = blockIdx.x;
  const int wg = (id & 7) * 24 + (id >> 3);
  const int bx = wg % 12, by = wg / 12;
  const int m0 = by * 256, n0 = bx * 256;
  const int K = DIM;

  // staging: thread writes phys byte tid*16 of an 8KB subpanel; its global source is the
  // swizzle-inverse logical position (row = l>>6, colByte = l&63 within [128][32] bf16).
  const int swl  = (tid * 16) ^ (((tid >> 5) & 1) << 5);
  const int srow = swl >> 6;            // 0..127
  const int scol = (swl & 63) >> 1;     // 0,8,16,24 (bf16 elts)
  const __hip_bfloat16* Asrc = A  + (size_t)(m0 + srow) * K + scol;
  const __hip_bfloat16* Bsrc = Bt + (size_t)(n0 + srow) * K + scol;
  __hip_bfloat16* ldsw = &lds[w * 512]; // wave slice of each subpanel

  // fragment-read column swizzle (elts): quad*8 ^ ((row>>3)&1)<<4, row bit3 == ln bit3
  const int acol = (quad * 8) ^ (((ln >> 3) & 1) << 4);

#define SPA(b,h,kk) ((((b)*2 + (h))*2 + (kk)) * 4096)
#define SPB(b,h,kk) (32768 + SPA(b,h,kk))
#define STAGE_A(b,h,k) do { \
    gld_lds16(Asrc + (size_t)((h)*128) * K + (k),      ldsw + SPA(b,h,0)); \
    gld_lds16(Asrc + (size_t)((h)*128) * K + (k) + 32, ldsw + SPA(b,h,1)); } while (0)
#define STAGE_B(b,h,k) do { \
    gld_lds16(Bsrc + (size_t)((h)*128) * K + (k),      ldsw + SPB(b,h,0)); \
    gld_lds16(Bsrc + (size_t)((h)*128) * K + (k) + 32, ldsw + SPB(b,h,1)); } while (0)

  bf16x8 af[4][2], bf[2][2];
  f32x4 acc[8][4] = {};

#define LDA(b, mh) do { _Pragma("unroll") \
    for (int i = 0; i < 4; i++) { \
      af[i][0] = *(const bf16x8*)&lds[SPA(b, wr, 0) + (((mh)*4 + i)*16 + ln)*32 + acol]; \
      af[i][1] = *(const bf16x8*)&lds[SPA(b, wr, 1) + (((mh)*4 + i)*16 + ln)*32 + acol]; } } while (0)
#define LDB(b, nh) do { _Pragma("unroll") \
    for (int j = 0; j < 2; j++) { \
      bf[j][0] = *(const bf16x8*)&lds[SPB(b, wc>>1, 0) + ((wc&1)*64 + ((nh)*2 + j)*16 + ln)*32 + acol]; \
      bf[j][1] = *(const bf16x8*)&lds[SPB(b, wc>>1, 1) + ((wc&1)*64 + ((nh)*2 + j)*16 + ln)*32 + acol]; } } while (0)
#define MMAC(mh, nh) do { __builtin_amdgcn_s_setprio(1); \
    _Pragma("unroll") for (int i = 0; i < 4; i++) \
      _Pragma("unroll") for (int j = 0; j < 2; j++) { \
        acc[(mh)*4+i][(nh)*2+j] = __builtin_amdgcn_mfma_f32_16x16x32_bf16(af[i][0], bf[j][0], acc[(mh)*4+i][(nh)*2+j], 0,0,0); \
        acc[(mh)*4+i][(nh)*2+j] = __builtin_amdgcn_mfma_f32_16x16x32_bf16(af[i][1], bf[j][1], acc[(mh)*4+i][(nh)*2+j], 0,0,0); } \
    __builtin_amdgcn_s_setprio(0); } while (0)

  // prologue: stage tile 0 into buf0, full drain
  STAGE_A(0, 0, 0); STAGE_A(0, 1, 0); STAGE_B(0, 0, 0); STAGE_B(0, 1, 0);
  ENDBAR_VM0;

  for (int T = 0; T < 31; T++) {
    const int b = T & 1, nb = b ^ 1;
    const int k1 = (T + 1) * 64;
    // q0: quadrant (0,0); stage A-h0 of T+1
    LDA(b, 0); LDB(b, 0);
    STAGE_A(nb, 0, k1);
    MIDBAR; MMAC(0, 0); ENDBAR;
    // q1: (0,1); stage A-h1
    LDB(b, 1);
    STAGE_A(nb, 1, k1);
    MIDBAR; MMAC(0, 1); ENDBAR;
    // q2: (1,1); stage B-h0 + B-h1 (B region freed since q0; last stage >=1 phase before drain)
    LDA(b, 1);
    STAGE_B(nb, 0, k1); STAGE_B(nb, 1, k1);
    MIDBAR; MMAC(1, 1); ENDBAR;
    // q3: (1,0); no stage; drain once per K-tile
    LDB(b, 0);
    MIDBAR; MMAC(1, 0); ENDBAR_VM0;
  }
  // tail: tile 31 in buf1, no staging
  LDA(1, 0); LDB(1, 0); MIDBAR; MMAC(0, 0); ENDBAR;
  LDB(1, 1);            MIDBAR; MMAC(0, 1); ENDBAR;
  LDA(1, 1);            MIDBAR; MMAC(1, 1); ENDBAR;
  LDB(1, 0);            MIDBAR; MMAC(1, 0);

  // epilogue: rope + head-major scatter. region block-uniform (n0 multiple of 256; 2048, 2560 are
  // multiples of 256 -> each block entirely Q, K, or V).
  const int region = (n0 >= 2560) ? 2 : (n0 >= 2048 ? 1 : 0);
  #pragma unroll
  for (int mf = 0; mf < 8; mf++) {
    #pragma unroll
    for (int nf = 0; nf < 4; nf++) {
      const int n = n0 + wc * 64 + nf * 16 + ln;
      const int d = n & 63;
      #pragma unroll
      for (int r = 0; r < 4; r++) {
        const int m = m0 + wr * 128 + mf * 16 + quad * 4 + r;
        const int bb = m >> 11, s = m & 2047;
        float v = acc[mf][nf][r];
        if (region == 2) {
          Vb[((size_t)(bb * NKV + ((n - 2560) >> 6)) * SEQ + s) * HD + d] = __float2bfloat16(v);
        } else {
          float p = __shfl_xor(v, 1);
          const float2 fc = *(const float2*)&freqs[s * 64 + (d & ~1)];
          float o = (d & 1) ? (v * fc.x + p * fc.y) : (v * fc.x - p * fc.y);
          if (region == 0)
            Qb[((size_t)(bb * NH + (n >> 6)) * SEQ + s) * HD + d] = __float2bfloat16(o * QSCALE);
          else
            Kb[((size_t)(bb * NKV + ((n - 2048) >> 6)) * SEQ + s) * HD + d] = __float2bfloat16(o);
        }
      }
    }
  }
#undef SPA
#undef SPB
#undef STAGE_A
#undef STAGE_B
#undef LDA
#undef LDB
#undef MMAC
}

// ---------------- WO GEMM, 4-wave 128x128, BK=32 dbuf, counted-vmcnt pipeline, fp32 out --------
// grid 512: wg = (id&7)*64 + id>>3; bx = wg&15, by = wg>>4.
__global__ __launch_bounds__(256) void gemm_wo_kernel(const __hip_bfloat16* __restrict__ A,
                                                      const __hip_bfloat16* __restrict__ Bt,
                                                      float* __restrict__ C) {
  __shared__ __hip_bfloat16 As[2][128 * 32];
  __shared__ __hip_bfloat16 Bs[2][128 * 32];
  const int tid = threadIdx.x;
  const int w = tid >> 6, lane = tid & 63, ln = lane & 15, quad = lane >> 4;
  const int wr = w >> 1, wc = w & 1;
  const int id = blockIdx.x;
  const int wg = (id & 7) * 64 + (id >> 3);
  const int bx = wg & 15, by = wg >> 4;
  const int m0 = by * 128, n0 = bx * 128;
  const int K = DIM, N = DIM;
  const __hip_bfloat16* Ag = A + (size_t)(m0 + w * 16 + (lane >> 2)) * K + (lane & 3) * 8;
  const __hip_bfloat16* Bg = Bt + (size_t)(n0 + w * 16 + (lane >> 2)) * K + (lane & 3) * 8;
  f32x4 acc[4][4] = {};

  auto stage = [&](int buf, int k) {
    gld_lds16(Ag + k, &As[buf][w * 512]);
    gld_lds16(Ag + (size_t)64 * K + k, &As[buf][w * 512 + 2048]);
    gld_lds16(Bg + k, &Bs[buf][w * 512]);
    gld_lds16(Bg + (size_t)64 * K + k, &Bs[buf][w * 512 + 2048]);
  };
  auto compute = [&](int buf) {
    bf16x8 af[4], bf[4];
    #pragma unroll
    for (int i = 0; i < 4; i++)
      af[i] = *(const bf16x8*)&As[buf][(wr * 64 + i * 16 + ln) * 32 + quad * 8];
    #pragma unroll
    for (int j = 0; j < 4; j++)
      bf[j] = *(const bf16x8*)&Bs[buf][(wc * 64 + j * 16 + ln) * 32 + quad * 8];
    #pragma unroll
    for (int i = 0; i < 4; i++)
      #pragma unroll
      for (int j = 0; j < 4; j++)
        acc[i][j] = __builtin_amdgcn_mfma_f32_16x16x32_bf16(af[i], bf[j], acc[i][j], 0, 0, 0);
  };

  stage(0, 0);
  stage(1, 32);
  for (int k0 = 0; k0 + 64 < K; k0 += 64) {
    PHASE_SYNC4;
    compute(0);
    POST_SYNC;
    stage(0, k0 + 64);
    PHASE_SYNC4;
    compute(1);
    POST_SYNC;
    stage(1, k0 + 96);
  }
  PHASE_SYNC4;
  compute(0);
  PHASE_SYNC0;
  compute(1);

  #pragma unroll
  for (int i = 0; i < 4; i++) {
    const int r0 = m0 + wr * 64 + i * 16 + quad * 4;
    #pragma unroll
    for (int j = 0; j < 4; j++) {
      const int cc = n0 + wc * 64 + j * 16 + ln;
      #pragma unroll
      for (int r = 0; r < 4; r++)
        C[(size_t)(r0 + r) * N + cc] = acc[i][j][r];
    }
  }
}

// ---------------- flash-style causal GQA attention ----------------
// No-max softmax (Q pre-scaled by log2e/8; P = exp2(s)).
// grid 1024 (1-D, XCD-swizzled): xcd = id&7 owns (b,kvh) combos {2*xcd, 2*xcd+1};
// within combo: t = 15-(slot>>2) (LPT), head group g = slot&3.
// 4 waves x 32 q-rows (128-row q-tile); KV tile 128 per barrier-pair, two 64-KV sub-rounds.
__global__ __launch_bounds__(256, 3) void attn_kernel(const __hip_bfloat16* __restrict__ Q,
                                                      const __hip_bfloat16* __restrict__ Kg,
                                                      const __hip_bfloat16* __restrict__ Vg,
                                                      __hip_bfloat16* __restrict__ O) {
  __shared__ __hip_bfloat16 Ks[128 * 64];     // chunk-swizzled: phys = kv*8 + (dBlk ^ (kv&7))
  __shared__ __hip_bfloat16 Vs[64 * 136];     // [d][s ^ ((d>>4&3)<<4)], stride 136
  __shared__ __hip_bfloat16 Ps[4][32 * 72];   // per-wave P, col ^ (quad<<4), stride 72
  const int id = blockIdx.x;
  const int xcd = id & 7, slot = id >> 3;
  const int cmb = xcd * 2 + (slot >> 6);      // 0..15
  const int b = cmb >> 3, kvh = cmb & 7;
  const int s_ = slot & 63;
  const int t = 15 - (s_ >> 2);               // big tiles first per XCD
  const int h = kvh * 4 + (s_ & 3);
  const int tid = threadIdx.x, w = tid >> 6, lane = tid & 63, ln = lane & 15, quad = lane >> 4;
  const size_t qbase = (size_t)(b * NH + h) * SEQ * HD;
  const size_t kbase = (size_t)(b * NKV + kvh) * SEQ * HD;

  // K gld lane mapping: phys chunk = c*256 + tid -> kv = phys>>3, dBlk = (phys&7)^(kv&7)
  const __hip_bfloat16* Kgl = Kg + kbase + (size_t)(tid >> 3) * 64 + (size_t)(((tid & 7) ^ ((tid >> 3) & 7)) * 8);
  // V scatter mapping (2-way free)
  const int vrow = tid >> 2, vcb = (tid & 3) * 16, vsw = (tid & 3) << 4;
  const int psw = ((ln >> 2) & 3) << 4;

  const int qgw = t * 128 + w * 32;
  bf16x8 qf[2][2];
  #pragma unroll
  for (int f = 0; f < 2; f++)
    #pragma unroll
    for (int kt = 0; kt < 2; kt++)
      qf[f][kt] = *(const bf16x8*)(Q + qbase + (size_t)(qgw + f * 16 + ln) * HD + kt * 32 + quad * 8);
  f32x4 Oacc[2][4] = {};
  float lrow[2][4] = {};
  union { unsigned short u[8]; bf16x8 v; } onesu;
  #pragma unroll
  for (int i = 0; i < 8; i++) onesu.u[i] = 0x3F80;
  const bf16x8 ones = onesu.v;

  // preload V tile 0
  uint4 vd[2][2];
  #pragma unroll
  for (int bt = 0; bt < 2; bt++)
    #pragma unroll
    for (int cc = 0; cc < 2; cc++)
      vd[bt][cc] = *(const uint4*)(Vg + kbase + (size_t)(bt * 64 + vrow) * HD + vcb + cc * 8);

  for (int j = 0; j <= t; j++) {
    // async K stage (16 KB, 4 calls) + V scatter from regs
    #pragma unroll
    for (int c = 0; c < 4; c++)
      gld_lds16(Kgl + (size_t)j * 8192 + c * 2048, &Ks[c * 2048 + w * 512]);
    #pragma unroll
    for (int bt = 0; bt < 2; bt++)
      #pragma unroll
      for (int cc = 0; cc < 2; cc++) {
        const __hip_bfloat16* vp = (const __hip_bfloat16*)&vd[bt][cc];
        const int col = vcb + cc * 8;
        const int sr = (bt * 64 + vrow) ^ vsw;
        #pragma unroll
        for (int e = 0; e < 8; e++)
          Vs[(col + e) * 136 + sr] = vp[e];
      }
    __syncthreads();
    // prefetch next V tile (stays in flight through compute)
    if (j < t) {
      #pragma unroll
      for (int bt = 0; bt < 2; bt++)
        #pragma unroll
        for (int cc = 0; cc < 2; cc++)
          vd[bt][cc] = *(const uint4*)(Vg + kbase + (size_t)((j + 1) * 128 + bt * 64 + vrow) * HD + vcb + cc * 8);
    }
    const bool lastIter = (j == t);
    #pragma unroll
    for (int s2 = 0; s2 < 2; s2++) {
      if (lastIter && s2 * 64 > w * 32 + 31) continue;   // wave entirely above diagonal
      bf16x8 kf[4][2];
      #pragma unroll
      for (int nt = 0; nt < 4; nt++)
        #pragma unroll
        for (int kt = 0; kt < 2; kt++) {
          const int kv = s2 * 64 + nt * 16 + ln;
          kf[nt][kt] = *(const bf16x8*)&Ks[(kv * 8 + ((kt * 4 + quad) ^ (ln & 7))) * 8];
        }
      #pragma unroll
      for (int f = 0; f < 2; f++) {
        if (lastIter && s2 * 64 > w * 32 + f * 16 + 15) continue;
        f32x4 sf[4];
        #pragma unroll
        for (int nt = 0; nt < 4; nt++) {
          f32x4 s = {};
          s = __builtin_amdgcn_mfma_f32_16x16x32_bf16(qf[f][0], kf[nt][0], s, 0, 0, 0);
          s = __builtin_amdgcn_mfma_f32_16x16x32_bf16(qf[f][1], kf[nt][1], s, 0, 0, 0);
          sf[nt] = s;
        }
        if (lastIter && s2 * 64 + 63 > w * 32 + f * 16) {
          const int qr = w * 32 + f * 16 + quad * 4;
          #pragma unroll
          for (int nt = 0; nt < 4; nt++) {
            const int kg = s2 * 64 + nt * 16 + ln;
            #pragma unroll
            for (int r = 0; r < 4; r++)
              if (kg > qr + r) sf[nt][r] = -1.0e38f;
          }
        }
        #pragma unroll
        for (int nt = 0; nt < 4; nt++)
          #pragma unroll
          for (int r = 0; r < 4; r++)
            Ps[w][(f * 16 + quad * 4 + r) * 72 + ((nt * 16 + ln) ^ (quad << 4))] =
                __float2bfloat16(EXP2F(sf[nt][r]));
      }
      #pragma unroll
      for (int f = 0; f < 2; f++) {
        if (lastIter && s2 * 64 > w * 32 + f * 16 + 15) continue;
        f32x4 ls = {};
        #pragma unroll
        for (int kt = 0; kt < 2; kt++) {
          bf16x8 pf = *(const bf16x8*)&Ps[w][(f * 16 + ln) * 72 + ((kt * 32 + quad * 8) ^ psw)];
          ls = __builtin_amdgcn_mfma_f32_16x16x32_bf16(pf, ones, ls, 0, 0, 0);
          #pragma unroll
          for (int dt = 0; dt < 4; dt++) {
            bf16x8 vf = *(const bf16x8*)&Vs[(dt * 16 + ln) * 136 + s2 * 64 + ((kt * 32 + quad * 8) ^ (dt << 4))];
            Oacc[f][dt] = __builtin_amdgcn_mfma_f32_16x16x32_bf16(pf, vf, Oacc[f][dt], 0, 0, 0);
          }
        }
        #pragma unroll
        for (int r = 0; r < 4; r++) lrow[f][r] += ls[r];
      }
    }
    __syncthreads();   // protects Ks/Vs before next staging; all waves reach it
  }
  // epilogue: out[b][s][h*64+d] = O/l
  #pragma unroll
  for (int f = 0; f < 2; f++) {
    const int so = qgw + f * 16 + quad * 4;
    #pragma unroll
    for (int r = 0; r < 4; r++) {
      const float inv = 1.0f / lrow[f][r];
      #pragma unroll
      for (int dt = 0; dt < 4; dt++)
        O[((size_t)(b * SEQ) + so + r) * DIM + h * HD + dt * 16 + ln] =
            __float2bfloat16(Oacc[f][dt][r] * inv);
    }
  }
}

extern "C" void kernel_launch(void* const* d_in, const int* in_sizes, int n_in,
                              void* d_out, int out_size, void* d_ws, size_t ws_size,
                              hipStream_t stream) {
  const float* x     = (const float*)d_in[0];
  const float* freqs = (const float*)d_in[1];
  const float* wqkv  = (const float*)d_in[2];
  const float* wo    = (const float*)d_in[3];
  float* out = (float*)d_out;

  char* ws = (char*)d_ws;
  __hip_bfloat16* xb    = (__hip_bfloat16*)ws; ws += (size_t)MTOT * DIM * 2;
  __hip_bfloat16* wqkvT = (__hip_bfloat16*)ws; ws += (size_t)QKV_N * DIM * 2;
  __hip_bfloat16* woT   = (__hip_bfloat16*)ws; ws += (size_t)DIM * DIM * 2;
  __hip_bfloat16* Qb    = (__hip_bfloat16*)ws; ws += (size_t)BATCH * NH * SEQ * HD * 2;
  __hip_bfloat16* Kb    = (__hip_bfloat16*)ws; ws += (size_t)BATCH * NKV * SEQ * HD * 2;
  __hip_bfloat16* Vb    = (__hip_bfloat16*)ws; ws += (size_t)BATCH * NKV * SEQ * HD * 2;
  __hip_bfloat16* attnb = (__hip_bfloat16*)ws; ws += (size_t)MTOT * DIM * 2;

  cvt_x_kernel<<<(MTOT * DIM / 4 + 255) / 256, 256, 0, stream>>>(x, xb, MTOT * DIM / 4);
  transpose_cvt_kernel<<<dim3(QKV_N / 32, DIM / 32), 256, 0, stream>>>(wqkv, wqkvT, DIM, QKV_N);
  transpose_cvt_kernel<<<dim3(DIM / 32, DIM / 32), 256, 0, stream>>>(wo, woT, DIM, DIM);
  gemm_qkv_rope_kernel<<<192, 512, 0, stream>>>(xb, wqkvT, freqs, Qb, Kb, Vb);
  attn_kernel<<<1024, 256, 0, stream>>>(Qb, Kb, Vb, attnb);
  gemm_wo_kernel<<<512, 256, 0, stream>>>(attnb, woT, out);
}

// Round 6
// 333.116 us; speedup vs baseline: 1.0013x; 1.0013x over previous
//
#include <hip/hip_runtime.h>
#include <hip/hip_bf16.h>
#include <math.h>

#define DIM 2048
#define NH 32
#define NKV 8
#define HD 64
#define SEQ 2048
#define BATCH 2
#define MTOT (BATCH*SEQ)          // 4096
#define QKV_N ((NH + 2*NKV)*HD)   // 3072
#define QSCALE 0.18033688011112042f   // log2(e)/8

typedef __bf16 bf16x8 __attribute__((ext_vector_type(8)));
typedef float f32x4 __attribute__((ext_vector_type(4)));

#if __has_builtin(__builtin_amdgcn_exp2f)
#define EXP2F __builtin_amdgcn_exp2f
#else
#define EXP2F exp2f
#endif

__device__ __forceinline__ void gld_lds16(const void* g, void* l) {
  __builtin_amdgcn_global_load_lds((__attribute__((address_space(1))) void*)g,
                                   (__attribute__((address_space(3))) void*)l,
                                   16, 0, 0);
}

// Counted-vmcnt phase sync (T3+T4): wait for the OLDER staged panel only (4 loads stay
// in flight), then barrier. Fused in one asm so no LDS read can be scheduled between
// the wait and the barrier (cross-wave staging hazard).
#define PHASE_SYNC4 asm volatile("s_waitcnt vmcnt(4)\n\ts_barrier" ::: "memory")
#define PHASE_SYNC0 asm volatile("s_waitcnt vmcnt(0)\n\ts_barrier" ::: "memory")
// After compute: own ds_reads done (lgkmcnt), barrier, THEN overwrite the consumed buffer.
#define POST_SYNC   asm volatile("s_waitcnt lgkmcnt(0)\n\ts_barrier" ::: "memory")

// ---------------- elementwise: fp32 -> bf16 ----------------
__global__ void cvt_x_kernel(const float* __restrict__ src, __hip_bfloat16* __restrict__ dst, int n4) {
  int i = blockIdx.x * 256 + threadIdx.x;
  if (i >= n4) return;
  float4 v = ((const float4*)src)[i];
  union { __hip_bfloat16 h[4]; uint2 u; } t;
  t.h[0] = __float2bfloat16(v.x); t.h[1] = __float2bfloat16(v.y);
  t.h[2] = __float2bfloat16(v.z); t.h[3] = __float2bfloat16(v.w);
  ((uint2*)dst)[i] = t.u;
}

// ---------------- transpose + convert: src R x C fp32 -> dst C x R bf16 ----------------
__global__ void transpose_cvt_kernel(const float* __restrict__ src, __hip_bfloat16* __restrict__ dst,
                                     int R, int C) {
  __shared__ float tile[32][33];
  int c0 = blockIdx.x * 32, r0 = blockIdx.y * 32;
  int tx = threadIdx.x & 31, ty = threadIdx.x >> 5;
  #pragma unroll
  for (int i = ty; i < 32; i += 8)
    tile[i][tx] = src[(size_t)(r0 + i) * C + c0 + tx];
  __syncthreads();
  #pragma unroll
  for (int i = ty; i < 32; i += 8)
    dst[(size_t)(c0 + i) * R + r0 + tx] = __float2bfloat16(tile[tx][i]);
}

// ---------------- QKV GEMM, 4-wave 128x128, BK=32 dbuf, counted-vmcnt pipeline, fused RoPE ------
// (R4 best-known: 86.5 us, ~600 TF. 128^2 gives grid 768 = 3/CU exact; 256^2 gives 192 < 256 CUs
// and regressed — tile choice dominated by grid/CU divisibility on this shape.)
// Main loop NEVER drains vmcnt to 0: panel t+1 (4 loads/wave) stays in flight through
// compute of panel t. grid 768 (XCD-swizzled, bijective): wg=(id&7)*96+id>>3; bx=wg%24, by=wg/24.
__global__ __launch_bounds__(256) void gemm_qkv_rope_kernel(const __hip_bfloat16* __restrict__ A,
                                                            const __hip_bfloat16* __restrict__ Bt,
                                                            const float* __restrict__ freqs,
                                                            __hip_bfloat16* __restrict__ Qb,
                                                            __hip_bfloat16* __restrict__ Kb,
                                                            __hip_bfloat16* __restrict__ Vb) {
  __shared__ __hip_bfloat16 As[2][128 * 32];   // double buffer, 16 KB
  __shared__ __hip_bfloat16 Bs[2][128 * 32];   // 16 KB
  const int tid = threadIdx.x;
  const int w = tid >> 6, lane = tid & 63, ln = lane & 15, quad = lane >> 4;
  const int wr = w >> 1, wc = w & 1;        // 2x2 wave grid, each wave owns 64x64
  const int id = blockIdx.x;
  const int wg = (id & 7) * 96 + (id >> 3);
  const int bx = wg % 24, by = wg / 24;
  const int m0 = by * 128, n0 = bx * 128;
  const int K = DIM;
  const __hip_bfloat16* Ag = A + (size_t)(m0 + w * 16 + (lane >> 2)) * K + (lane & 3) * 8;
  const __hip_bfloat16* Bg = Bt + (size_t)(n0 + w * 16 + (lane >> 2)) * K + (lane & 3) * 8;
  f32x4 acc[4][4] = {};

  auto stage = [&](int buf, int k) {   // 4 VMEM ops per wave
    gld_lds16(Ag + k, &As[buf][w * 512]);
    gld_lds16(Ag + (size_t)64 * K + k, &As[buf][w * 512 + 2048]);
    gld_lds16(Bg + k, &Bs[buf][w * 512]);
    gld_lds16(Bg + (size_t)64 * K + k, &Bs[buf][w * 512 + 2048]);
  };
  auto compute = [&](int buf) {
    bf16x8 af[4], bf[4];
    #pragma unroll
    for (int i = 0; i < 4; i++)
      af[i] = *(const bf16x8*)&As[buf][(wr * 64 + i * 16 + ln) * 32 + quad * 8];
    #pragma unroll
    for (int j = 0; j < 4; j++)
      bf[j] = *(const bf16x8*)&Bs[buf][(wc * 64 + j * 16 + ln) * 32 + quad * 8];
    #pragma unroll
    for (int i = 0; i < 4; i++)
      #pragma unroll
      for (int j = 0; j < 4; j++)
        acc[i][j] = __builtin_amdgcn_mfma_f32_16x16x32_bf16(af[i], bf[j], acc[i][j], 0, 0, 0);
  };

  stage(0, 0);
  stage(1, 32);          // 8 loads in flight
  for (int k0 = 0; k0 + 64 < K; k0 += 64) {   // 31 iters; stages panels k0+64, k0+96 (<=2016)
    PHASE_SYNC4;         // oldest 4 (panel k0) landed; 4 newer stay in flight
    compute(0);
    POST_SYNC;           // buf0 consumed by all waves
    stage(0, k0 + 64);
    PHASE_SYNC4;         // panel k0+32 landed
    compute(1);
    POST_SYNC;
    stage(1, k0 + 96);
  }
  PHASE_SYNC4;           // panel K-64 landed (4 of panel K-32 still in flight)
  compute(0);
  PHASE_SYNC0;           // final panel landed
  compute(1);

  // epilogue: rope + head-major scatter. region is block-uniform (n0 multiple of 128; 2048,2560 are too)
  const int region = (n0 >= 2560) ? 2 : (n0 >= 2048 ? 1 : 0);
  #pragma unroll
  for (int i = 0; i < 4; i++) {
    #pragma unroll
    for (int j = 0; j < 4; j++) {
      const int n = n0 + wc * 64 + j * 16 + ln;
      const int d = n & 63;
      #pragma unroll
      for (int r = 0; r < 4; r++) {
        const int m = m0 + wr * 64 + i * 16 + quad * 4 + r;
        const int bb = m >> 11, s = m & 2047;
        float v = acc[i][j][r];
        if (region == 2) {
          Vb[((size_t)(bb * NKV + ((n - 2560) >> 6)) * SEQ + s) * HD + d] = __float2bfloat16(v);
        } else {
          float p = __shfl_xor(v, 1);
          const float2 fc = *(const float2*)&freqs[s * 64 + (d & ~1)];
          float o = (d & 1) ? (v * fc.x + p * fc.y) : (v * fc.x - p * fc.y);
          if (region == 0)
            Qb[((size_t)(bb * NH + (n >> 6)) * SEQ + s) * HD + d] = __float2bfloat16(o * QSCALE);
          else
            Kb[((size_t)(bb * NKV + ((n - 2048) >> 6)) * SEQ + s) * HD + d] = __float2bfloat16(o);
        }
      }
    }
  }
}

// ---------------- WO GEMM, 4-wave 128x128, BK=32 dbuf, counted-vmcnt pipeline, fp32 out --------
// grid 512: wg = (id&7)*64 + id>>3; bx = wg&15, by = wg>>4.
__global__ __launch_bounds__(256) void gemm_wo_kernel(const __hip_bfloat16* __restrict__ A,
                                                      const __hip_bfloat16* __restrict__ Bt,
                                                      float* __restrict__ C) {
  __shared__ __hip_bfloat16 As[2][128 * 32];
  __shared__ __hip_bfloat16 Bs[2][128 * 32];
  const int tid = threadIdx.x;
  const int w = tid >> 6, lane = tid & 63, ln = lane & 15, quad = lane >> 4;
  const int wr = w >> 1, wc = w & 1;
  const int id = blockIdx.x;
  const int wg = (id & 7) * 64 + (id >> 3);
  const int bx = wg & 15, by = wg >> 4;
  const int m0 = by * 128, n0 = bx * 128;
  const int K = DIM, N = DIM;
  const __hip_bfloat16* Ag = A + (size_t)(m0 + w * 16 + (lane >> 2)) * K + (lane & 3) * 8;
  const __hip_bfloat16* Bg = Bt + (size_t)(n0 + w * 16 + (lane >> 2)) * K + (lane & 3) * 8;
  f32x4 acc[4][4] = {};

  auto stage = [&](int buf, int k) {
    gld_lds16(Ag + k, &As[buf][w * 512]);
    gld_lds16(Ag + (size_t)64 * K + k, &As[buf][w * 512 + 2048]);
    gld_lds16(Bg + k, &Bs[buf][w * 512]);
    gld_lds16(Bg + (size_t)64 * K + k, &Bs[buf][w * 512 + 2048]);
  };
  auto compute = [&](int buf) {
    bf16x8 af[4], bf[4];
    #pragma unroll
    for (int i = 0; i < 4; i++)
      af[i] = *(const bf16x8*)&As[buf][(wr * 64 + i * 16 + ln) * 32 + quad * 8];
    #pragma unroll
    for (int j = 0; j < 4; j++)
      bf[j] = *(const bf16x8*)&Bs[buf][(wc * 64 + j * 16 + ln) * 32 + quad * 8];
    #pragma unroll
    for (int i = 0; i < 4; i++)
      #pragma unroll
      for (int j = 0; j < 4; j++)
        acc[i][j] = __builtin_amdgcn_mfma_f32_16x16x32_bf16(af[i], bf[j], acc[i][j], 0, 0, 0);
  };

  stage(0, 0);
  stage(1, 32);
  for (int k0 = 0; k0 + 64 < K; k0 += 64) {
    PHASE_SYNC4;
    compute(0);
    POST_SYNC;
    stage(0, k0 + 64);
    PHASE_SYNC4;
    compute(1);
    POST_SYNC;
    stage(1, k0 + 96);
  }
  PHASE_SYNC4;
  compute(0);
  PHASE_SYNC0;
  compute(1);

  #pragma unroll
  for (int i = 0; i < 4; i++) {
    const int r0 = m0 + wr * 64 + i * 16 + quad * 4;
    #pragma unroll
    for (int j = 0; j < 4; j++) {
      const int cc = n0 + wc * 64 + j * 16 + ln;
      #pragma unroll
      for (int r = 0; r < 4; r++)
        C[(size_t)(r0 + r) * N + cc] = acc[i][j][r];
    }
  }
}

// ---------------- flash-style causal GQA attention ----------------
// No-max softmax (Q pre-scaled by log2e/8; P = exp2(s)).
// T14 async-STAGE on K: K tile j+1 is loaded into registers during compute of tile j
// (issued right after the staging barrier -> full compute phase of latency cover), then
// ds_write_b128 to the SAME swizzled phys addresses gld_lds produced. The staging barrier
// now drains only LDS writes, not in-flight VMEM (was: 4 gld_lds immediately before a
// full-drain __syncthreads = exposed L2/HBM latency per tile).
// grid 1024 (1-D, XCD-swizzled): xcd = id&7 owns (b,kvh) combos {2*xcd, 2*xcd+1};
// within combo: t = 15-(slot>>2) (LPT), head group g = slot&3.
// 4 waves x 32 q-rows (128-row q-tile); KV tile 128 per barrier-pair, two 64-KV sub-rounds.
__global__ __launch_bounds__(256, 3) void attn_kernel(const __hip_bfloat16* __restrict__ Q,
                                                      const __hip_bfloat16* __restrict__ Kg,
                                                      const __hip_bfloat16* __restrict__ Vg,
                                                      __hip_bfloat16* __restrict__ O) {
  __shared__ __hip_bfloat16 Ks[128 * 64];     // chunk-swizzled: phys = kv*8 + (dBlk ^ (kv&7))
  __shared__ __hip_bfloat16 Vs[64 * 136];     // [d][s ^ ((d>>4&3)<<4)], stride 136
  __shared__ __hip_bfloat16 Ps[4][32 * 72];   // per-wave P, col ^ (quad<<4), stride 72
  const int id = blockIdx.x;
  const int xcd = id & 7, slot = id >> 3;
  const int cmb = xcd * 2 + (slot >> 6);      // 0..15
  const int b = cmb >> 3, kvh = cmb & 7;
  const int s_ = slot & 63;
  const int t = 15 - (s_ >> 2);               // big tiles first per XCD
  const int h = kvh * 4 + (s_ & 3);
  const int tid = threadIdx.x, w = tid >> 6, lane = tid & 63, ln = lane & 15, quad = lane >> 4;
  const size_t qbase = (size_t)(b * NH + h) * SEQ * HD;
  const size_t kbase = (size_t)(b * NKV + kvh) * SEQ * HD;

  // K lane mapping (same phys layout as the old gld_lds path):
  // phys chunk = c*256 + tid -> kv = phys>>3, dBlk = (phys&7)^(kv&7)
  const __hip_bfloat16* Kgl = Kg + kbase + (size_t)(tid >> 3) * 64 + (size_t)(((tid & 7) ^ ((tid >> 3) & 7)) * 8);
  // per-thread LDS dest (elem offset): old gld_lds dest base + lane*8 elems
  const int kdst = w * 512 + lane * 8;
  // V scatter mapping (2-way free)
  const int vrow = tid >> 2, vcb = (tid & 3) * 16, vsw = (tid & 3) << 4;
  const int psw = ((ln >> 2) & 3) << 4;

  const int qgw = t * 128 + w * 32;
  bf16x8 qf[2][2];
  #pragma unroll
  for (int f = 0; f < 2; f++)
    #pragma unroll
    for (int kt = 0; kt < 2; kt++)
      qf[f][kt] = *(const bf16x8*)(Q + qbase + (size_t)(qgw + f * 16 + ln) * HD + kt * 32 + quad * 8);
  f32x4 Oacc[2][4] = {};
  float lrow[2][4] = {};
  union { unsigned short u[8]; bf16x8 v; } onesu;
  #pragma unroll
  for (int i = 0; i < 8; i++) onesu.u[i] = 0x3F80;
  const bf16x8 ones = onesu.v;

  // preload K tile 0 and V tile 0 into regs
  uint4 kd[4];
  #pragma unroll
  for (int c = 0; c < 4; c++)
    kd[c] = *(const uint4*)(Kgl + c * 2048);
  uint4 vd[2][2];
  #pragma unroll
  for (int bt = 0; bt < 2; bt++)
    #pragma unroll
    for (int cc = 0; cc < 2; cc++)
      vd[bt][cc] = *(const uint4*)(Vg + kbase + (size_t)(bt * 64 + vrow) * HD + vcb + cc * 8);

  for (int j = 0; j <= t; j++) {
    // staging phase: all from registers (ds_write only; barrier drain is cheap)
    #pragma unroll
    for (int c = 0; c < 4; c++)
      *(uint4*)&Ks[c * 2048 + kdst] = kd[c];
    #pragma unroll
    for (int bt = 0; bt < 2; bt++)
      #pragma unroll
      for (int cc = 0; cc < 2; cc++) {
        const __hip_bfloat16* vp = (const __hip_bfloat16*)&vd[bt][cc];
        const int col = vcb + cc * 8;
        const int sr = (bt * 64 + vrow) ^ vsw;
        #pragma unroll
        for (int e = 0; e < 8; e++)
          Vs[(col + e) * 136 + sr] = vp[e];
      }
    __syncthreads();
    // prefetch next K + V tiles (stay in flight through the whole compute phase)
    if (j < t) {
      #pragma unroll
      for (int c = 0; c < 4; c++)
        kd[c] = *(const uint4*)(Kgl + (size_t)(j + 1) * 8192 + c * 2048);
      #pragma unroll
      for (int bt = 0; bt < 2; bt++)
        #pragma unroll
        for (int cc = 0; cc < 2; cc++)
          vd[bt][cc] = *(const uint4*)(Vg + kbase + (size_t)((j + 1) * 128 + bt * 64 + vrow) * HD + vcb + cc * 8);
    }
    const bool lastIter = (j == t);
    #pragma unroll
    for (int s2 = 0; s2 < 2; s2++) {
      if (lastIter && s2 * 64 > w * 32 + 31) continue;   // wave entirely above diagonal
      bf16x8 kf[4][2];
      #pragma unroll
      for (int nt = 0; nt < 4; nt++)
        #pragma unroll
        for (int kt = 0; kt < 2; kt++) {
          const int kv = s2 * 64 + nt * 16 + ln;
          kf[nt][kt] = *(const bf16x8*)&Ks[(kv * 8 + ((kt * 4 + quad) ^ (ln & 7))) * 8];
        }
      #pragma unroll
      for (int f = 0; f < 2; f++) {
        if (lastIter && s2 * 64 > w * 32 + f * 16 + 15) continue;
        f32x4 sf[4];
        #pragma unroll
        for (int nt = 0; nt < 4; nt++) {
          f32x4 s = {};
          s = __builtin_amdgcn_mfma_f32_16x16x32_bf16(qf[f][0], kf[nt][0], s, 0, 0, 0);
          s = __builtin_amdgcn_mfma_f32_16x16x32_bf16(qf[f][1], kf[nt][1], s, 0, 0, 0);
          sf[nt] = s;
        }
        if (lastIter && s2 * 64 + 63 > w * 32 + f * 16) {
          const int qr = w * 32 + f * 16 + quad * 4;
          #pragma unroll
          for (int nt = 0; nt < 4; nt++) {
            const int kg = s2 * 64 + nt * 16 + ln;
            #pragma unroll
            for (int r = 0; r < 4; r++)
              if (kg > qr + r) sf[nt][r] = -1.0e38f;
          }
        }
        #pragma unroll
        for (int nt = 0; nt < 4; nt++)
          #pragma unroll
          for (int r = 0; r < 4; r++)
            Ps[w][(f * 16 + quad * 4 + r) * 72 + ((nt * 16 + ln) ^ (quad << 4))] =
                __float2bfloat16(EXP2F(sf[nt][r]));
      }
      #pragma unroll
      for (int f = 0; f < 2; f++) {
        if (lastIter && s2 * 64 > w * 32 + f * 16 + 15) continue;
        f32x4 ls = {};
        #pragma unroll
        for (int kt = 0; kt < 2; kt++) {
          bf16x8 pf = *(const bf16x8*)&Ps[w][(f * 16 + ln) * 72 + ((kt * 32 + quad * 8) ^ psw)];
          ls = __builtin_amdgcn_mfma_f32_16x16x32_bf16(pf, ones, ls, 0, 0, 0);
          #pragma unroll
          for (int dt = 0; dt < 4; dt++) {
            bf16x8 vf = *(const bf16x8*)&Vs[(dt * 16 + ln) * 136 + s2 * 64 + ((kt * 32 + quad * 8) ^ (dt << 4))];
            Oacc[f][dt] = __builtin_amdgcn_mfma_f32_16x16x32_bf16(pf, vf, Oacc[f][dt], 0, 0, 0);
          }
        }
        #pragma unroll
        for (int r = 0; r < 4; r++) lrow[f][r] += ls[r];
      }
    }
    __syncthreads();   // protects Ks/Vs before next staging; all waves reach it
  }
  // epilogue: out[b][s][h*64+d] = O/l
  #pragma unroll
  for (int f = 0; f < 2; f++) {
    const int so = qgw + f * 16 + quad * 4;
    #pragma unroll
    for (int r = 0; r < 4; r++) {
      const float inv = 1.0f / lrow[f][r];
      #pragma unroll
      for (int dt = 0; dt < 4; dt++)
        O[((size_t)(b * SEQ) + so + r) * DIM + h * HD + dt * 16 + ln] =
            __float2bfloat16(Oacc[f][dt][r] * inv);
    }
  }
}

extern "C" void kernel_launch(void* const* d_in, const int* in_sizes, int n_in,
                              void* d_out, int out_size, void* d_ws, size_t ws_size,
                              hipStream_t stream) {
  const float* x     = (const float*)d_in[0];
  const float* freqs = (const float*)d_in[1];
  const float* wqkv  = (const float*)d_in[2];
  const float* wo    = (const float*)d_in[3];
  float* out = (float*)d_out;

  char* ws = (char*)d_ws;
  __hip_bfloat16* xb    = (__hip_bfloat16*)ws; ws += (size_t)MTOT * DIM * 2;
  __hip_bfloat16* wqkvT = (__hip_bfloat16*)ws; ws += (size_t)QKV_N * DIM * 2;
  __hip_bfloat16* woT   = (__hip_bfloat16*)ws; ws += (size_t)DIM * DIM * 2;
  __hip_bfloat16* Qb    = (__hip_bfloat16*)ws; ws += (size_t)BATCH * NH * SEQ * HD * 2;
  __hip_bfloat16* Kb    = (__hip_bfloat16*)ws; ws += (size_t)BATCH * NKV * SEQ * HD * 2;
  __hip_bfloat16* Vb    = (__hip_bfloat16*)ws; ws += (size_t)BATCH * NKV * SEQ * HD * 2;
  __hip_bfloat16* attnb = (__hip_bfloat16*)ws; ws += (size_t)MTOT * DIM * 2;

  cvt_x_kernel<<<(MTOT * DIM / 4 + 255) / 256, 256, 0, stream>>>(x, xb, MTOT * DIM / 4);
  transpose_cvt_kernel<<<dim3(QKV_N / 32, DIM / 32), 256, 0, stream>>>(wqkv, wqkvT, DIM, QKV_N);
  transpose_cvt_kernel<<<dim3(DIM / 32, DIM / 32), 256, 0, stream>>>(wo, woT, DIM, DIM);
  gemm_qkv_rope_kernel<<<768, 256, 0, stream>>>(xb, wqkvT, freqs, Qb, Kb, Vb);
  attn_kernel<<<1024, 256, 0, stream>>>(Qb, Kb, Vb, attnb);
  gemm_wo_kernel<<<512, 256, 0, stream>>>(attnb, woT, out);
}

// Round 7
// 326.589 us; speedup vs baseline: 1.0213x; 1.0200x over previous
//
#include <hip/hip_runtime.h>
#include <hip/hip_bf16.h>
#include <math.h>

#define DIM 2048
#define NH 32
#define NKV 8
#define HD 64
#define SEQ 2048
#define BATCH 2
#define MTOT (BATCH*SEQ)          // 4096
#define QKV_N ((NH + 2*NKV)*HD)   // 3072
#define QSCALE 0.18033688011112042f   // log2(e)/8

typedef __bf16 bf16x8 __attribute__((ext_vector_type(8)));
typedef float f32x4 __attribute__((ext_vector_type(4)));

#if __has_builtin(__builtin_amdgcn_exp2f)
#define EXP2F __builtin_amdgcn_exp2f
#else
#define EXP2F exp2f
#endif

__device__ __forceinline__ void gld_lds16(const void* g, void* l) {
  __builtin_amdgcn_global_load_lds((__attribute__((address_space(1))) void*)g,
                                   (__attribute__((address_space(3))) void*)l,
                                   16, 0, 0);
}

// Counted-vmcnt phase sync (T3+T4), 2-deep: wait until only the 8 NEWEST loads (2 panels)
// remain outstanding -> the oldest panel has landed. Fused asm so no LDS read can be
// scheduled between the wait and the barrier (cross-wave staging hazard).
#define PHASE_SYNC8 asm volatile("s_waitcnt vmcnt(8)\n\ts_barrier" ::: "memory")
#define PHASE_SYNC4 asm volatile("s_waitcnt vmcnt(4)\n\ts_barrier" ::: "memory")
#define PHASE_SYNC0 asm volatile("s_waitcnt vmcnt(0)\n\ts_barrier" ::: "memory")
// After compute: own ds_reads done (lgkmcnt), barrier, THEN overwrite the consumed buffer.
#define POST_SYNC   asm volatile("s_waitcnt lgkmcnt(0)\n\ts_barrier" ::: "memory")

// ---------------- elementwise: fp32 -> bf16 ----------------
__global__ void cvt_x_kernel(const float* __restrict__ src, __hip_bfloat16* __restrict__ dst, int n4) {
  int i = blockIdx.x * 256 + threadIdx.x;
  if (i >= n4) return;
  float4 v = ((const float4*)src)[i];
  union { __hip_bfloat16 h[4]; uint2 u; } t;
  t.h[0] = __float2bfloat16(v.x); t.h[1] = __float2bfloat16(v.y);
  t.h[2] = __float2bfloat16(v.z); t.h[3] = __float2bfloat16(v.w);
  ((uint2*)dst)[i] = t.u;
}

// ---------------- transpose + convert: src R x C fp32 -> dst C x R bf16 ----------------
__global__ void transpose_cvt_kernel(const float* __restrict__ src, __hip_bfloat16* __restrict__ dst,
                                     int R, int C) {
  __shared__ float tile[32][33];
  int c0 = blockIdx.x * 32, r0 = blockIdx.y * 32;
  int tx = threadIdx.x & 31, ty = threadIdx.x >> 5;
  #pragma unroll
  for (int i = ty; i < 32; i += 8)
    tile[i][tx] = src[(size_t)(r0 + i) * C + c0 + tx];
  __syncthreads();
  #pragma unroll
  for (int i = ty; i < 32; i += 8)
    dst[(size_t)(c0 + i) * R + r0 + tx] = __float2bfloat16(tile[tx][i]);
}

// ---------------- QKV GEMM, 4-wave 128x128, BK=32 TRIPLE-buffer 2-deep counted pipeline ---------
// Panels T+1 and T+2 (8 loads/wave) stay in flight through compute of panel T; vmcnt(8)
// in steady state, never 0 until the tail. LDS 48 KB -> still 3 blocks/CU.
// grid 768 (XCD-swizzled, bijective): wg=(id&7)*96+id>>3; bx=wg%24, by=wg/24.
__global__ __launch_bounds__(256) void gemm_qkv_rope_kernel(const __hip_bfloat16* __restrict__ A,
                                                            const __hip_bfloat16* __restrict__ Bt,
                                                            const float* __restrict__ freqs,
                                                            __hip_bfloat16* __restrict__ Qb,
                                                            __hip_bfloat16* __restrict__ Kb,
                                                            __hip_bfloat16* __restrict__ Vb) {
  __shared__ __hip_bfloat16 As[3][128 * 32];   // triple buffer, 24 KB
  __shared__ __hip_bfloat16 Bs[3][128 * 32];   // 24 KB
  const int tid = threadIdx.x;
  const int w = tid >> 6, lane = tid & 63, ln = lane & 15, quad = lane >> 4;
  const int wr = w >> 1, wc = w & 1;        // 2x2 wave grid, each wave owns 64x64
  const int id = blockIdx.x;
  const int wg = (id & 7) * 96 + (id >> 3);
  const int bx = wg % 24, by = wg / 24;
  const int m0 = by * 128, n0 = bx * 128;
  const int K = DIM;
  const __hip_bfloat16* Ag = A + (size_t)(m0 + w * 16 + (lane >> 2)) * K + (lane & 3) * 8;
  const __hip_bfloat16* Bg = Bt + (size_t)(n0 + w * 16 + (lane >> 2)) * K + (lane & 3) * 8;
  f32x4 acc[4][4] = {};

  auto stage = [&](int buf, int k) {   // 4 VMEM ops per wave
    gld_lds16(Ag + k, &As[buf][w * 512]);
    gld_lds16(Ag + (size_t)64 * K + k, &As[buf][w * 512 + 2048]);
    gld_lds16(Bg + k, &Bs[buf][w * 512]);
    gld_lds16(Bg + (size_t)64 * K + k, &Bs[buf][w * 512 + 2048]);
  };
  auto compute = [&](int buf) {
    bf16x8 af[4], bf[4];
    #pragma unroll
    for (int i = 0; i < 4; i++)
      af[i] = *(const bf16x8*)&As[buf][(wr * 64 + i * 16 + ln) * 32 + quad * 8];
    #pragma unroll
    for (int j = 0; j < 4; j++)
      bf[j] = *(const bf16x8*)&Bs[buf][(wc * 64 + j * 16 + ln) * 32 + quad * 8];
    #pragma unroll
    for (int i = 0; i < 4; i++)
      #pragma unroll
      for (int j = 0; j < 4; j++)
        acc[i][j] = __builtin_amdgcn_mfma_f32_16x16x32_bf16(af[i], bf[j], acc[i][j], 0, 0, 0);
  };

  // prologue: 3 panels (12 loads) in flight
  stage(0, 0);
  stage(1, 32);
  stage(2, 64);
  // steady state: panels 0..60; invariant 12 outstanding before wait, 8 after
  for (int T = 0; T < 61; T++) {
    PHASE_SYNC8;                 // oldest panel (T) landed; panels T+1,T+2 in flight
    compute(T % 3);
    POST_SYNC;                   // buf (T%3) consumed by all waves
    stage(T % 3, (T + 3) * 32);  // stage panel T+3 (max 63*32 = 2016)
  }
  // tail: panels 61,62,63 in bufs 1,2,0
  PHASE_SYNC8; compute(1);
  PHASE_SYNC4; compute(2);
  PHASE_SYNC0; compute(0);

  // epilogue: rope + head-major scatter. region is block-uniform (n0 multiple of 128; 2048,2560 are too)
  const int region = (n0 >= 2560) ? 2 : (n0 >= 2048 ? 1 : 0);
  #pragma unroll
  for (int i = 0; i < 4; i++) {
    #pragma unroll
    for (int j = 0; j < 4; j++) {
      const int n = n0 + wc * 64 + j * 16 + ln;
      const int d = n & 63;
      #pragma unroll
      for (int r = 0; r < 4; r++) {
        const int m = m0 + wr * 64 + i * 16 + quad * 4 + r;
        const int bb = m >> 11, s = m & 2047;
        float v = acc[i][j][r];
        if (region == 2) {
          Vb[((size_t)(bb * NKV + ((n - 2560) >> 6)) * SEQ + s) * HD + d] = __float2bfloat16(v);
        } else {
          float p = __shfl_xor(v, 1);
          const float2 fc = *(const float2*)&freqs[s * 64 + (d & ~1)];
          float o = (d & 1) ? (v * fc.x + p * fc.y) : (v * fc.x - p * fc.y);
          if (region == 0)
            Qb[((size_t)(bb * NH + (n >> 6)) * SEQ + s) * HD + d] = __float2bfloat16(o * QSCALE);
          else
            Kb[((size_t)(bb * NKV + ((n - 2048) >> 6)) * SEQ + s) * HD + d] = __float2bfloat16(o);
        }
      }
    }
  }
}

// ---------------- WO GEMM, 4-wave 128x128, BK=32 triple-buffer 2-deep pipeline, fp32 out --------
// grid 512: wg = (id&7)*64 + id>>3; bx = wg&15, by = wg>>4.
__global__ __launch_bounds__(256) void gemm_wo_kernel(const __hip_bfloat16* __restrict__ A,
                                                      const __hip_bfloat16* __restrict__ Bt,
                                                      float* __restrict__ C) {
  __shared__ __hip_bfloat16 As[3][128 * 32];
  __shared__ __hip_bfloat16 Bs[3][128 * 32];
  const int tid = threadIdx.x;
  const int w = tid >> 6, lane = tid & 63, ln = lane & 15, quad = lane >> 4;
  const int wr = w >> 1, wc = w & 1;
  const int id = blockIdx.x;
  const int wg = (id & 7) * 64 + (id >> 3);
  const int bx = wg & 15, by = wg >> 4;
  const int m0 = by * 128, n0 = bx * 128;
  const int K = DIM, N = DIM;
  const __hip_bfloat16* Ag = A + (size_t)(m0 + w * 16 + (lane >> 2)) * K + (lane & 3) * 8;
  const __hip_bfloat16* Bg = Bt + (size_t)(n0 + w * 16 + (lane >> 2)) * K + (lane & 3) * 8;
  f32x4 acc[4][4] = {};

  auto stage = [&](int buf, int k) {
    gld_lds16(Ag + k, &As[buf][w * 512]);
    gld_lds16(Ag + (size_t)64 * K + k, &As[buf][w * 512 + 2048]);
    gld_lds16(Bg + k, &Bs[buf][w * 512]);
    gld_lds16(Bg + (size_t)64 * K + k, &Bs[buf][w * 512 + 2048]);
  };
  auto compute = [&](int buf) {
    bf16x8 af[4], bf[4];
    #pragma unroll
    for (int i = 0; i < 4; i++)
      af[i] = *(const bf16x8*)&As[buf][(wr * 64 + i * 16 + ln) * 32 + quad * 8];
    #pragma unroll
    for (int j = 0; j < 4; j++)
      bf[j] = *(const bf16x8*)&Bs[buf][(wc * 64 + j * 16 + ln) * 32 + quad * 8];
    #pragma unroll
    for (int i = 0; i < 4; i++)
      #pragma unroll
      for (int j = 0; j < 4; j++)
        acc[i][j] = __builtin_amdgcn_mfma_f32_16x16x32_bf16(af[i], bf[j], acc[i][j], 0, 0, 0);
  };

  stage(0, 0);
  stage(1, 32);
  stage(2, 64);
  for (int T = 0; T < 61; T++) {
    PHASE_SYNC8;
    compute(T % 3);
    POST_SYNC;
    stage(T % 3, (T + 3) * 32);
  }
  PHASE_SYNC8; compute(1);
  PHASE_SYNC4; compute(2);
  PHASE_SYNC0; compute(0);

  #pragma unroll
  for (int i = 0; i < 4; i++) {
    const int r0 = m0 + wr * 64 + i * 16 + quad * 4;
    #pragma unroll
    for (int j = 0; j < 4; j++) {
      const int cc = n0 + wc * 64 + j * 16 + ln;
      #pragma unroll
      for (int r = 0; r < 4; r++)
        C[(size_t)(r0 + r) * N + cc] = acc[i][j][r];
    }
  }
}

// ---------------- flash-style causal GQA attention (R4 version, reverted) ----------------
// No-max softmax (Q pre-scaled by log2e/8; P = exp2(s)).
// K staged via global_load_lds (pre-swizzled source; T14 reg-staging on K was net-negative
// per catalog note — reg-staging only where forced, i.e. V's transpose).
// grid 1024 (1-D, XCD-swizzled): xcd = id&7 owns (b,kvh) combos {2*xcd, 2*xcd+1};
// within combo: t = 15-(slot>>2) (LPT), head group g = slot&3.
// 4 waves x 32 q-rows (128-row q-tile); KV tile 128 per barrier-pair, two 64-KV sub-rounds.
__global__ __launch_bounds__(256, 3) void attn_kernel(const __hip_bfloat16* __restrict__ Q,
                                                      const __hip_bfloat16* __restrict__ Kg,
                                                      const __hip_bfloat16* __restrict__ Vg,
                                                      __hip_bfloat16* __restrict__ O) {
  __shared__ __hip_bfloat16 Ks[128 * 64];     // chunk-swizzled: phys = kv*8 + (dBlk ^ (kv&7))
  __shared__ __hip_bfloat16 Vs[64 * 136];     // [d][s ^ ((d>>4&3)<<4)], stride 136
  __shared__ __hip_bfloat16 Ps[4][32 * 72];   // per-wave P, col ^ (quad<<4), stride 72
  const int id = blockIdx.x;
  const int xcd = id & 7, slot = id >> 3;
  const int cmb = xcd * 2 + (slot >> 6);      // 0..15
  const int b = cmb >> 3, kvh = cmb & 7;
  const int s_ = slot & 63;
  const int t = 15 - (s_ >> 2);               // big tiles first per XCD
  const int h = kvh * 4 + (s_ & 3);
  const int tid = threadIdx.x, w = tid >> 6, lane = tid & 63, ln = lane & 15, quad = lane >> 4;
  const size_t qbase = (size_t)(b * NH + h) * SEQ * HD;
  const size_t kbase = (size_t)(b * NKV + kvh) * SEQ * HD;

  // K gld lane mapping: phys chunk = c*256 + tid -> kv = phys>>3, dBlk = (phys&7)^(kv&7)
  const __hip_bfloat16* Kgl = Kg + kbase + (size_t)(tid >> 3) * 64 + (size_t)(((tid & 7) ^ ((tid >> 3) & 7)) * 8);
  // V scatter mapping (2-way free)
  const int vrow = tid >> 2, vcb = (tid & 3) * 16, vsw = (tid & 3) << 4;
  const int psw = ((ln >> 2) & 3) << 4;

  const int qgw = t * 128 + w * 32;
  bf16x8 qf[2][2];
  #pragma unroll
  for (int f = 0; f < 2; f++)
    #pragma unroll
    for (int kt = 0; kt < 2; kt++)
      qf[f][kt] = *(const bf16x8*)(Q + qbase + (size_t)(qgw + f * 16 + ln) * HD + kt * 32 + quad * 8);
  f32x4 Oacc[2][4] = {};
  float lrow[2][4] = {};
  union { unsigned short u[8]; bf16x8 v; } onesu;
  #pragma unroll
  for (int i = 0; i < 8; i++) onesu.u[i] = 0x3F80;
  const bf16x8 ones = onesu.v;

  // preload V tile 0
  uint4 vd[2][2];
  #pragma unroll
  for (int bt = 0; bt < 2; bt++)
    #pragma unroll
    for (int cc = 0; cc < 2; cc++)
      vd[bt][cc] = *(const uint4*)(Vg + kbase + (size_t)(bt * 64 + vrow) * HD + vcb + cc * 8);

  for (int j = 0; j <= t; j++) {
    // async K stage (16 KB, 4 calls) + V scatter from regs
    #pragma unroll
    for (int c = 0; c < 4; c++)
      gld_lds16(Kgl + (size_t)j * 8192 + c * 2048, &Ks[c * 2048 + w * 512]);
    #pragma unroll
    for (int bt = 0; bt < 2; bt++)
      #pragma unroll
      for (int cc = 0; cc < 2; cc++) {
        const __hip_bfloat16* vp = (const __hip_bfloat16*)&vd[bt][cc];
        const int col = vcb + cc * 8;
        const int sr = (bt * 64 + vrow) ^ vsw;
        #pragma unroll
        for (int e = 0; e < 8; e++)
          Vs[(col + e) * 136 + sr] = vp[e];
      }
    __syncthreads();
    // prefetch next V tile (stays in flight through compute)
    if (j < t) {
      #pragma unroll
      for (int bt = 0; bt < 2; bt++)
        #pragma unroll
        for (int cc = 0; cc < 2; cc++)
          vd[bt][cc] = *(const uint4*)(Vg + kbase + (size_t)((j + 1) * 128 + bt * 64 + vrow) * HD + vcb + cc * 8);
    }
    const bool lastIter = (j == t);
    #pragma unroll
    for (int s2 = 0; s2 < 2; s2++) {
      if (lastIter && s2 * 64 > w * 32 + 31) continue;   // wave entirely above diagonal
      bf16x8 kf[4][2];
      #pragma unroll
      for (int nt = 0; nt < 4; nt++)
        #pragma unroll
        for (int kt = 0; kt < 2; kt++) {
          const int kv = s2 * 64 + nt * 16 + ln;
          kf[nt][kt] = *(const bf16x8*)&Ks[(kv * 8 + ((kt * 4 + quad) ^ (ln & 7))) * 8];
        }
      #pragma unroll
      for (int f = 0; f < 2; f++) {
        if (lastIter && s2 * 64 > w * 32 + f * 16 + 15) continue;
        f32x4 sf[4];
        #pragma unroll
        for (int nt = 0; nt < 4; nt++) {
          f32x4 s = {};
          s = __builtin_amdgcn_mfma_f32_16x16x32_bf16(qf[f][0], kf[nt][0], s, 0, 0, 0);
          s = __builtin_amdgcn_mfma_f32_16x16x32_bf16(qf[f][1], kf[nt][1], s, 0, 0, 0);
          sf[nt] = s;
        }
        if (lastIter && s2 * 64 + 63 > w * 32 + f * 16) {
          const int qr = w * 32 + f * 16 + quad * 4;
          #pragma unroll
          for (int nt = 0; nt < 4; nt++) {
            const int kg = s2 * 64 + nt * 16 + ln;
            #pragma unroll
            for (int r = 0; r < 4; r++)
              if (kg > qr + r) sf[nt][r] = -1.0e38f;
          }
        }
        #pragma unroll
        for (int nt = 0; nt < 4; nt++)
          #pragma unroll
          for (int r = 0; r < 4; r++)
            Ps[w][(f * 16 + quad * 4 + r) * 72 + ((nt * 16 + ln) ^ (quad << 4))] =
                __float2bfloat16(EXP2F(sf[nt][r]));
      }
      #pragma unroll
      for (int f = 0; f < 2; f++) {
        if (lastIter && s2 * 64 > w * 32 + f * 16 + 15) continue;
        f32x4 ls = {};
        #pragma unroll
        for (int kt = 0; kt < 2; kt++) {
          bf16x8 pf = *(const bf16x8*)&Ps[w][(f * 16 + ln) * 72 + ((kt * 32 + quad * 8) ^ psw)];
          ls = __builtin_amdgcn_mfma_f32_16x16x32_bf16(pf, ones, ls, 0, 0, 0);
          #pragma unroll
          for (int dt = 0; dt < 4; dt++) {
            bf16x8 vf = *(const bf16x8*)&Vs[(dt * 16 + ln) * 136 + s2 * 64 + ((kt * 32 + quad * 8) ^ (dt << 4))];
            Oacc[f][dt] = __builtin_amdgcn_mfma_f32_16x16x32_bf16(pf, vf, Oacc[f][dt], 0, 0, 0);
          }
        }
        #pragma unroll
        for (int r = 0; r < 4; r++) lrow[f][r] += ls[r];
      }
    }
    __syncthreads();   // protects Ks/Vs before next staging; all waves reach it
  }
  // epilogue: out[b][s][h*64+d] = O/l
  #pragma unroll
  for (int f = 0; f < 2; f++) {
    const int so = qgw + f * 16 + quad * 4;
    #pragma unroll
    for (int r = 0; r < 4; r++) {
      const float inv = 1.0f / lrow[f][r];
      #pragma unroll
      for (int dt = 0; dt < 4; dt++)
        O[((size_t)(b * SEQ) + so + r) * DIM + h * HD + dt * 16 + ln] =
            __float2bfloat16(Oacc[f][dt][r] * inv);
    }
  }
}

extern "C" void kernel_launch(void* const* d_in, const int* in_sizes, int n_in,
                              void* d_out, int out_size, void* d_ws, size_t ws_size,
                              hipStream_t stream) {
  const float* x     = (const float*)d_in[0];
  const float* freqs = (const float*)d_in[1];
  const float* wqkv  = (const float*)d_in[2];
  const float* wo    = (const float*)d_in[3];
  float* out = (float*)d_out;

  char* ws = (char*)d_ws;
  __hip_bfloat16* xb    = (__hip_bfloat16*)ws; ws += (size_t)MTOT * DIM * 2;
  __hip_bfloat16* wqkvT = (__hip_bfloat16*)ws; ws += (size_t)QKV_N * DIM * 2;
  __hip_bfloat16* woT   = (__hip_bfloat16*)ws; ws += (size_t)DIM * DIM * 2;
  __hip_bfloat16* Qb    = (__hip_bfloat16*)ws; ws += (size_t)BATCH * NH * SEQ * HD * 2;
  __hip_bfloat16* Kb    = (__hip_bfloat16*)ws; ws += (size_t)BATCH * NKV * SEQ * HD * 2;
  __hip_bfloat16* Vb    = (__hip_bfloat16*)ws; ws += (size_t)BATCH * NKV * SEQ * HD * 2;
  __hip_bfloat16* attnb = (__hip_bfloat16*)ws; ws += (size_t)MTOT * DIM * 2;

  cvt_x_kernel<<<(MTOT * DIM / 4 + 255) / 256, 256, 0, stream>>>(x, xb, MTOT * DIM / 4);
  transpose_cvt_kernel<<<dim3(QKV_N / 32, DIM / 32), 256, 0, stream>>>(wqkv, wqkvT, DIM, QKV_N);
  transpose_cvt_kernel<<<dim3(DIM / 32, DIM / 32), 256, 0, stream>>>(wo, woT, DIM, DIM);
  gemm_qkv_rope_kernel<<<768, 256, 0, stream>>>(xb, wqkvT, freqs, Qb, Kb, Vb);
  attn_kernel<<<1024, 256, 0, stream>>>(Qb, Kb, Vb, attnb);
  gemm_wo_kernel<<<512, 256, 0, stream>>>(attnb, woT, out);
}